// Round 16
// baseline (99.134 us; speedup 1.0000x reference)
//
#include <hip/hip_runtime.h>

typedef _Float16 half8 __attribute__((ext_vector_type(8)));
typedef float f32x4 __attribute__((ext_vector_type(4)));

#define WD 7
#define NPAD 128
#define KDIM 8330
#define BSZ 4096
#define SPLITK 8
#define NTILES 131        // ceil(8330/64); splits 0-2: 17 tiles, 3-7: 16
#define BM 64
#define BK 64

// ws layout (bytes)
static constexpr size_t OFF_WT   = 0;                          // _Float16 wt_tiled[131][2][128][8][8]
static constexpr size_t WT_BYTES = (size_t)NTILES * 32768;     // 4,292,608
static constexpr size_t OFF_BIAS = WT_BYTES;                   // 128 floats
static constexpr size_t OFF_PART = OFF_BIAS + 512;             // [8][4096][128] f32 = 16.8 MB

#define LDS_X_BYTES (3 * 64 * 64 * 4)      // 49152: 3 bufs x [64 rows][64 f32]
#define LDS_TOTAL   (LDS_X_BYTES + 32768)  // + W single buffer = 81920

static __device__ const int KIDX[5][4] = {
    {0, 1, 3, 4}, {7, 8, 9, 10}, {5, 6, 11, 12}, {11, 12, 13, 14}, {15, 16, 15, 16}};
static __device__ const unsigned long long OBASE[5] = {0ull, 401408ull, 802816ull, 1204224ull, 1605632ull};

__device__ __forceinline__ int tile0_of(int s) { return 16 * s + min(s, 3); }
__device__ __forceinline__ int niter_of(int s) { return (s < 3) ? 17 : 16; }

__device__ __forceinline__ unsigned pk16(_Float16 a, _Float16 b) {
  return (unsigned)__builtin_bit_cast(unsigned short, a) |
         ((unsigned)__builtin_bit_cast(unsigned short, b) << 16);
}

__device__ __forceinline__ void gload_lds4(const void* g, void* l) {
  __builtin_amdgcn_global_load_lds((const __attribute__((address_space(1))) unsigned int*)g,
                                   (__attribute__((address_space(3))) unsigned int*)l, 4, 0, 0);
}
__device__ __forceinline__ void gload_lds16(const void* g, void* l) {
  __builtin_amdgcn_global_load_lds((const __attribute__((address_space(1))) unsigned int*)g,
                                   (__attribute__((address_space(3))) unsigned int*)l, 16, 0, 0);
}

// ---------------- pack: one block = one BK=64 tile.
// wt_tiled[tile][comp][col][sp][8], content slot c at physical sp = c ^ (col&7).
__global__ __launch_bounds__(256) void pack_kernel(
    const float* __restrict__ Wh, const float* __restrict__ bh,
    const float* __restrict__ Wa, const float* __restrict__ ba,
    const float* __restrict__ Wu, const float* __restrict__ bu,
    const float* __restrict__ Wl_, const float* __restrict__ bl,
    const float* __restrict__ Wf, const float* __restrict__ bf,
    char* __restrict__ wsb) {
  _Float16* wt = (_Float16*)(wsb + OFF_WT);
  float* bias = (float*)(wsb + OFF_BIAS);
  __shared__ _Float16 sh[64][128];
  __shared__ _Float16 sl[64][128];
  const int tile = blockIdx.x;
  const int k0 = tile * 64;
  const int tid = threadIdx.x;

#pragma unroll
  for (int jj = 0; jj < 32; ++jj) {
    int idx = tid + 256 * jj;
    int kk = idx >> 7, n = idx & 127;
    int k = k0 + kk;
    float w = 0.f;
    if (k < KDIM) {
      if      (n < 28)  w = Wh [k * 28 + n];
      else if (n < 56)  w = Wa [k * 28 + (n - 28)];
      else if (n < 84)  w = Wu [k * 28 + (n - 56)];
      else if (n < 112) w = Wl_[k * 28 + (n - 84)];
      else if (n < 126) w = Wf [k * 14 + (n - 112)];
    }
    _Float16 h = (_Float16)w;
    _Float16 l = (_Float16)((w - (float)h) * 2048.0f);
    sh[kk][n] = h;
    sl[kk][n] = l;
  }
  if (blockIdx.x == 0 && tid < NPAD) {
    int n = tid;
    float v = 0.f;
    if      (n < 28)  v = bh[n];
    else if (n < 56)  v = ba[n - 28];
    else if (n < 84)  v = bu[n - 56];
    else if (n < 112) v = bl[n - 84];
    else if (n < 126) v = bf[n - 112];
    bias[n] = v;
  }
  __syncthreads();
  const int n = tid >> 1;                    // col 0..127
  const int chalf = (tid & 1) * 4;           // content slots 0-3 or 4-7
  _Float16* tb = wt + (size_t)tile * 16384;  // [comp 8192][col 64][sp 8]
#pragma unroll
  for (int c4 = 0; c4 < 4; ++c4) {
    int c = chalf + c4;                      // content k-slot (k = c*8..c*8+7)
    int sp = c ^ (n & 7);                    // physical slot
    int kc = c * 8;
    uint4 qh, ql;
    qh.x = pk16(sh[kc + 0][n], sh[kc + 1][n]);
    qh.y = pk16(sh[kc + 2][n], sh[kc + 3][n]);
    qh.z = pk16(sh[kc + 4][n], sh[kc + 5][n]);
    qh.w = pk16(sh[kc + 6][n], sh[kc + 7][n]);
    ql.x = pk16(sl[kc + 0][n], sl[kc + 1][n]);
    ql.y = pk16(sl[kc + 2][n], sl[kc + 3][n]);
    ql.z = pk16(sl[kc + 4][n], sl[kc + 5][n]);
    ql.w = pk16(sl[kc + 6][n], sl[kc + 7][n]);
    *(uint4*)(tb + (size_t)n * 64 + sp * 8)        = qh;   // comp 0
    *(uint4*)(tb + 8192 + (size_t)n * 64 + sp * 8) = ql;   // comp 1
  }
}

// ---------------- GEMM: r15 structure, BK=64 (half the windows, 2x work each).
// Single W buffer (32KB) + triple x (48KB) = 80KB dynamic LDS, 2 blocks/CU.
// Two barriers/iter; counted vmcnt(16); DMA-only staging.
__global__ __launch_bounds__(256) void gemm_kernel(const float* __restrict__ x,
                                                   char* __restrict__ wsb) {
  extern __shared__ char ldsbuf[];
  float (*alds)[64][64] = (float(*)[64][64])ldsbuf;         // [3][row][64 f32]
  _Float16* wlds = (_Float16*)(ldsbuf + LDS_X_BYTES);       // [2][128][64]

  const _Float16* wt = (const _Float16*)(wsb + OFF_WT);
  float* partial = (float*)(wsb + OFF_PART);
  const int bid = blockIdx.x;
  const int split = bid & 7;                 // consecutive bids -> XCD round-robin
  const int row0 = (bid >> 3) * BM;
  const int tile0 = tile0_of(split);
  const int ks = tile0 * 64;
  const int niter = niter_of(split);

  const int tid = threadIdx.x;
  const int lane = tid & 63;
  const int wid = tid >> 6;
  const int wm = wid & 1;                    // row half (32)
  const int wn = wid >> 1;                   // col half (64)

  // ---- x DMA: 16 instrs/wave, each one 256B row; 16B-unit source permuted
  // by u ^ (row&15), linear LDS dest. Lane: u = lane>>2, f = lane&3.
  const int u_ln = lane >> 2;
  const int f_ln = lane & 3;
  const float* xsrc[16];
#pragma unroll
  for (int j = 0; j < 16; ++j) {
    int row = wid * 16 + j;
    int koff = ((u_ln ^ (row & 15)) << 2) + f_ln;
    xsrc[j] = x + (size_t)(row0 + row) * KDIM + koff;
  }
  auto stageX = [&](int buf, int kb) {
    if (kb + BK <= KDIM) {
#pragma unroll
      for (int j = 0; j < 16; ++j)
        gload_lds4((const void*)(xsrc[j] + kb), (void*)&alds[buf][wid * 16 + j][0]);
    } else {  // last tile of split 7 only; 16 vmem loads keep the count at 16
#pragma unroll
      for (int j = 0; j < 16; ++j) {
        int row = wid * 16 + j;
        int k = kb + ((u_ln ^ (row & 15)) << 2) + f_ln;
        float v = (k < KDIM) ? x[(size_t)(row0 + row) * KDIM + k] : 0.f;
        alds[buf][row][lane] = v;
      }
    }
  };

  // ---- W DMA: 8 instrs/wave, 1KB contiguous source -> linear dest
  auto stageW = [&](int tile) {
    const _Float16* src = wt + (size_t)tile * 16384 + (size_t)wid * 4096 + (size_t)lane * 8;
#pragma unroll
    for (int c = 0; c < 8; ++c) {
      int chunk = wid * 8 + c;
      gload_lds16((const void*)(src + c * 512),
                  (void*)((char*)wlds + chunk * 1024));
    }
  };

  f32x4 accA[2][4], accB[2][4];
#pragma unroll
  for (int mt = 0; mt < 2; ++mt)
#pragma unroll
    for (int nt = 0; nt < 4; ++nt) { accA[mt][nt] = (f32x4)(0.f); accB[mt][nt] = (f32x4)(0.f); }

  const int fr = lane & 15;
  const int fslot = lane >> 4;

  // ---- prologue: W(0), x(0) staged; x(1) in flight. Queue leaving: [x(1):16]
  stageW(tile0);
  stageX(0, ks);
  stageX(1, ks + BK);
  asm volatile("s_waitcnt vmcnt(16) lgkmcnt(0)" ::: "memory");
  __builtin_amdgcn_s_barrier();

  int xbuf = 0;
  for (int t = 0; t < niter; ++t) {
    // ---- phase 1: all LDS -> regs for tile t (both k-steps)
    float4 fA[2][2], fB[2][2];
    half8 b_h[2][4], b_l[2][4];
#pragma unroll
    for (int ks2 = 0; ks2 < 2; ++ks2)
#pragma unroll
      for (int mt = 0; mt < 2; ++mt) {
        int row = wm * 32 + mt * 16 + fr;
        int u0 = (ks2 * 8 + 2 * fslot) ^ (row & 15);
        int u1 = (ks2 * 8 + 2 * fslot + 1) ^ (row & 15);
        fA[ks2][mt] = *(const float4*)&alds[xbuf][row][u0 * 4];
        fB[ks2][mt] = *(const float4*)&alds[xbuf][row][u1 * 4];
      }
#pragma unroll
    for (int ks2 = 0; ks2 < 2; ++ks2)
#pragma unroll
      for (int nt = 0; nt < 4; ++nt) {
        int col = wn * 64 + nt * 16 + fr;
        int sp = (ks2 * 4 + fslot) ^ (col & 7);
        b_h[ks2][nt] = *(const half8*)(wlds + (size_t)col * 64 + sp * 8);
        b_l[ks2][nt] = *(const half8*)(wlds + 8192 + (size_t)col * 64 + sp * 8);
      }
    asm volatile("s_waitcnt lgkmcnt(0)" ::: "memory");
    __builtin_amdgcn_s_barrier();            // all reads of W buffer done

    // ---- phase 2: issue next stages (single W buffer now safe to overwrite)
    if (t + 1 < niter) stageW(tile0 + t + 1);
    if (t + 2 < niter) {
      int nb = xbuf + 2; if (nb >= 3) nb -= 3;
      stageX(nb, ks + (t + 2) * BK);
    }
    __builtin_amdgcn_sched_barrier(0);

    // ---- cvt + MFMA per k-step
#pragma unroll
    for (int ks2 = 0; ks2 < 2; ++ks2) {
      half8 a_h[2], a_l[2];
#pragma unroll
      for (int mt = 0; mt < 2; ++mt) {
        float fv[8] = {fA[ks2][mt].x, fA[ks2][mt].y, fA[ks2][mt].z, fA[ks2][mt].w,
                       fB[ks2][mt].x, fB[ks2][mt].y, fB[ks2][mt].z, fB[ks2][mt].w};
#pragma unroll
        for (int i = 0; i < 8; ++i) {
          _Float16 h = (_Float16)fv[i];
          a_h[mt][i] = h;
          a_l[mt][i] = (_Float16)((fv[i] - (float)h) * 2048.0f);
        }
      }
      __builtin_amdgcn_s_setprio(1);
#pragma unroll
      for (int mt = 0; mt < 2; ++mt)
#pragma unroll
        for (int nt = 0; nt < 4; ++nt) {
          accA[mt][nt] = __builtin_amdgcn_mfma_f32_16x16x32_f16(a_h[mt], b_h[ks2][nt], accA[mt][nt], 0, 0, 0);
          accB[mt][nt] = __builtin_amdgcn_mfma_f32_16x16x32_f16(a_l[mt], b_h[ks2][nt], accB[mt][nt], 0, 0, 0);
          accB[mt][nt] = __builtin_amdgcn_mfma_f32_16x16x32_f16(a_h[mt], b_l[ks2][nt], accB[mt][nt], 0, 0, 0);
        }
      __builtin_amdgcn_s_setprio(0);
    }

    // ---- trailing wait: retire W(t+1)+x(t+1); keep x(t+2):16 in flight
    if (t + 1 < niter) {
      if (t + 2 < niter)
        asm volatile("s_waitcnt vmcnt(16) lgkmcnt(0)" ::: "memory");
      else
        asm volatile("s_waitcnt vmcnt(0) lgkmcnt(0)" ::: "memory");
      __builtin_amdgcn_s_barrier();
    }
    ++xbuf; if (xbuf >= 3) xbuf = 0;
  }

  float* pb = partial + (size_t)split * BSZ * NPAD;
#pragma unroll
  for (int mt = 0; mt < 2; ++mt)
#pragma unroll
    for (int nt = 0; nt < 4; ++nt) {
      int col = wn * 64 + nt * 16 + fr;
#pragma unroll
      for (int r = 0; r < 4; ++r) {
        int row = row0 + wm * 32 + mt * 16 + fslot * 4 + r;
        pb[(size_t)row * NPAD + col] = accA[mt][nt][r] + accB[mt][nt][r] * (1.0f / 2048.0f);
      }
    }
}

// ---------------- fused reduce + epilogue (coalesced via LDS)
__device__ __forceinline__ void axis_mask(const float a[WD], int lo, int hi, float m[WD]) {
  float am[WD];
  float tot = 0.f;
#pragma unroll
  for (int c = 0; c < WD; ++c) { am[c] = (c >= lo) ? a[c] : 0.f; tot += am[c]; }
  float run = 0.f;
  float c1[WD];
#pragma unroll
  for (int c = 0; c < WD; ++c) {
    run += am[c] / tot;
    c1[c] = (run >= 0.3f) ? run : 0.f;
  }
  float tot2 = 0.f;
#pragma unroll
  for (int c = 0; c < WD; ++c) { am[c] = (c < hi) ? a[c] : 0.f; tot2 += am[c]; }
  run = 0.f;
#pragma unroll
  for (int c = 0; c < WD; ++c) {
    run += am[c] / tot2;
    float c2 = 1.f - run;
    c2 = (c2 >= 0.3f) ? c2 : 0.f;
    m[c] = c1[c] * c2;
  }
}

__global__ __launch_bounds__(256) void epi_kernel(const char* __restrict__ wsb,
                                                  const float* __restrict__ keypoint,
                                                  float* __restrict__ out) {
  __shared__ float vlds[64][132];
  const int b0 = blockIdx.x * 64;
  const int tid = threadIdx.x;
  const float4* part4 = (const float4*)(wsb + OFF_PART);
  const float4* bias4 = (const float4*)(wsb + OFF_BIAS);

  float4 a[8];
#pragma unroll
  for (int j = 0; j < 8; ++j) {
    int fi = tid * 8 + j;
    a[j] = part4[((size_t)(b0 + (fi >> 5))) * 32 + (fi & 31)];
  }
  for (int sp = 1; sp < SPLITK; ++sp) {
#pragma unroll
    for (int j = 0; j < 8; ++j) {
      int fi = tid * 8 + j;
      float4 p = part4[((size_t)sp * BSZ + b0 + (fi >> 5)) * 32 + (fi & 31)];
      a[j].x += p.x; a[j].y += p.y; a[j].z += p.z; a[j].w += p.w;
    }
  }
#pragma unroll
  for (int j = 0; j < 8; ++j) {
    int fi = tid * 8 + j;
    float4 bb = bias4[fi & 31];
    a[j].x += bb.x; a[j].y += bb.y; a[j].z += bb.z; a[j].w += bb.w;
    *(float4*)&vlds[fi >> 5][(fi & 31) * 4] = a[j];
  }
  __syncthreads();

  for (int u = tid; u < 64 * 5; u += 256) {
    int fam = u >> 6;
    int bl = u & 63;
    int b = b0 + bl;
    const int G = (fam == 4) ? 1 : 2;
    const int nk = (fam == 4) ? 2 : 4;
    const float* vv = &vlds[bl][fam * 28];

    int mnx = 7, mxx = -1, mny = 7, mxy = -1;
    for (int i = 0; i < nk; ++i) {
      int kidx = KIDX[fam][i];
      float fx = keypoint[((size_t)b * 17 + kidx) * 2 + 0];
      float fy = keypoint[((size_t)b * 17 + kidx) * 2 + 1];
      int ix = (int)floorf(fx * 7.0f); ix = ix < 6 ? ix : 6;
      int iy = (int)floorf(fy * 7.0f); iy = iy < 6 ? iy : 6;
      mnx = min(mnx, ix); mxx = max(mxx, ix);
      mny = min(mny, iy); mxy = max(mxy, iy);
    }
    int lox = mnx - 1; if (lox < 0) lox = 0;
    int hix = mxx + 1; if (hix > 6) hix = 6;
    int loy = mny - 1; if (loy < 0) loy = 0;
    int hiy = mxy + 1; if (hiy > 6) hiy = 6;

    float xmg[2][WD], ymg[2][WD];
    float mx = 0.f;
#pragma unroll
    for (int g = 0; g < 2; ++g) {
      if (g < G) {
        const float* vg = vv + g * 14;
        float a0[WD], a1[WD];
#pragma unroll
        for (int c = 0; c < WD; ++c) {
          float s0 = vg[c], s1 = vg[c + 7];
          float mM = fmaxf(s0, s1);
          float e0 = expf(s0 - mM), e1 = expf(s1 - mM);
          float sum = e0 + e1;
          a0[c] = expf(e0 / sum);
          a1[c] = expf(e1 / sum);
        }
        axis_mask(a0, lox, hix, xmg[g]);
        axis_mask(a1, loy, hiy, ymg[g]);
        float mx_x = 0.f, mx_y = 0.f;
#pragma unroll
        for (int c = 0; c < WD; ++c) {
          mx_x = fmaxf(mx_x, xmg[g][c]);
          mx_y = fmaxf(mx_y, ymg[g][c]);
        }
        mx = fmaxf(mx, mx_y * mx_x);
      }
    }

    float d = mx + 1e-7f;
    float* op = out + OBASE[fam] + (size_t)b * (G * 49);
#pragma unroll
    for (int g = 0; g < 2; ++g) {
      if (g < G) {
#pragma unroll
        for (int y = 0; y < WD; ++y) {
          float yv = ymg[g][y];
#pragma unroll
          for (int xx = 0; xx < WD; ++xx) {
            op[g * 49 + y * 7 + xx] = (yv * xmg[g][xx]) / d;
          }
        }
      }
    }
  }
}

extern "C" void kernel_launch(void* const* d_in, const int* in_sizes, int n_in,
                              void* d_out, int out_size, void* d_ws, size_t ws_size,
                              hipStream_t stream) {
  const float* x        = (const float*)d_in[0];
  const float* keypoint = (const float*)d_in[1];
  const float* Wh = (const float*)d_in[2];
  const float* bh = (const float*)d_in[3];
  const float* Wa = (const float*)d_in[4];
  const float* ba = (const float*)d_in[5];
  const float* Wu = (const float*)d_in[6];
  const float* bu = (const float*)d_in[7];
  const float* Wl = (const float*)d_in[8];
  const float* bl = (const float*)d_in[9];
  const float* Wf = (const float*)d_in[10];
  const float* bf = (const float*)d_in[11];
  float* out = (float*)d_out;
  char* wsb  = (char*)d_ws;

  (void)hipFuncSetAttribute(reinterpret_cast<const void*>(gemm_kernel),
                            hipFuncAttributeMaxDynamicSharedMemorySize, LDS_TOTAL);

  hipLaunchKernelGGL(pack_kernel, dim3(NTILES), dim3(256), 0, stream,
                     Wh, bh, Wa, ba, Wu, bu, Wl, bl, Wf, bf, wsb);
  hipLaunchKernelGGL(gemm_kernel, dim3((BSZ / BM) * SPLITK), dim3(256), LDS_TOTAL, stream,
                     x, wsb);
  hipLaunchKernelGGL(epi_kernel, dim3(BSZ / 64), dim3(256), 0, stream,
                     wsb, keypoint, out);
}

// Round 17
// 71.585 us; speedup vs baseline: 1.3848x; 1.3848x over previous
//
#include <hip/hip_runtime.h>

typedef _Float16 half8 __attribute__((ext_vector_type(8)));
typedef float f32x4 __attribute__((ext_vector_type(4)));

#define WD 7
#define NPAD 128
#define KDIM 8330
#define BSZ 4096
#define SPLITK 8
#define NTILES 261        // ceil(8330/32); splits 0-4: 33 tiles, splits 5-7: 32
#define BM 64
#define BK 32

// ws layout (bytes)
static constexpr size_t OFF_WT   = 0;                          // _Float16 wt_tiled[261][2][128][4][8]
static constexpr size_t WT_BYTES = (size_t)NTILES * 16384;     // 4,276,224
static constexpr size_t OFF_BIAS = WT_BYTES;                   // 128 floats
static constexpr size_t OFF_PART = OFF_BIAS + 512;             // [8][4096][128] f32 = 16.8 MB

static __device__ const int KIDX[5][4] = {
    {0, 1, 3, 4}, {7, 8, 9, 10}, {5, 6, 11, 12}, {11, 12, 13, 14}, {15, 16, 15, 16}};
static __device__ const unsigned long long OBASE[5] = {0ull, 401408ull, 802816ull, 1204224ull, 1605632ull};

__device__ __forceinline__ int tile0_of(int s) { return 33 * s - max(0, s - 5); }
__device__ __forceinline__ int niter_of(int s) { return (s < 5) ? 33 : 32; }

__device__ __forceinline__ unsigned pk16(_Float16 a, _Float16 b) {
  return (unsigned)__builtin_bit_cast(unsigned short, a) |
         ((unsigned)__builtin_bit_cast(unsigned short, b) << 16);
}

__device__ __forceinline__ void gload_lds4(const void* g, void* l) {
  __builtin_amdgcn_global_load_lds((const __attribute__((address_space(1))) unsigned int*)g,
                                   (__attribute__((address_space(3))) unsigned int*)l, 4, 0, 0);
}
__device__ __forceinline__ void gload_lds16(const void* g, void* l) {
  __builtin_amdgcn_global_load_lds((const __attribute__((address_space(1))) unsigned int*)g,
                                   (__attribute__((address_space(3))) unsigned int*)l, 16, 0, 0);
}

// ---------------- pack: W -> tiled, bank-swizzled fp16 hi/lo wt_tiled[tile][comp][col][s'][8]
__global__ __launch_bounds__(256) void pack_kernel(
    const float* __restrict__ Wh, const float* __restrict__ bh,
    const float* __restrict__ Wa, const float* __restrict__ ba,
    const float* __restrict__ Wu, const float* __restrict__ bu,
    const float* __restrict__ Wl_, const float* __restrict__ bl,
    const float* __restrict__ Wf, const float* __restrict__ bf,
    char* __restrict__ wsb) {
  _Float16* wt = (_Float16*)(wsb + OFF_WT);
  float* bias = (float*)(wsb + OFF_BIAS);
  __shared__ _Float16 sh[64][128];
  __shared__ _Float16 sl[64][128];
  const int k0 = blockIdx.x * 64;
  const int tid = threadIdx.x;

#pragma unroll
  for (int jj = 0; jj < 32; ++jj) {
    int idx = tid + 256 * jj;
    int kk = idx >> 7, n = idx & 127;
    int k = k0 + kk;
    float w = 0.f;
    if (k < KDIM) {
      if      (n < 28)  w = Wh [k * 28 + n];
      else if (n < 56)  w = Wa [k * 28 + (n - 28)];
      else if (n < 84)  w = Wu [k * 28 + (n - 56)];
      else if (n < 112) w = Wl_[k * 28 + (n - 84)];
      else if (n < 126) w = Wf [k * 14 + (n - 112)];
    }
    _Float16 h = (_Float16)w;
    _Float16 l = (_Float16)((w - (float)h) * 2048.0f);
    sh[kk][n] = h;
    sl[kk][n] = l;
  }
  if (blockIdx.x == 0 && tid < NPAD) {
    int n = tid;
    float v = 0.f;
    if      (n < 28)  v = bh[n];
    else if (n < 56)  v = ba[n - 28];
    else if (n < 84)  v = bu[n - 56];
    else if (n < 112) v = bl[n - 84];
    else if (n < 126) v = bf[n - 112];
    bias[n] = v;
  }
  __syncthreads();
  const int n = tid >> 1;
  const int kc = (tid & 1) * 32;
  const int kglob = k0 + kc;
  if (kglob < NTILES * 32) {
    const int tile = kglob >> 5;
    _Float16* tb = wt + (size_t)tile * 8192;      // [comp 4096][col 32][s' 8]
#pragma unroll
    for (int c = 0; c < 4; ++c) {                 // c = content k-slot
      int sp = c ^ ((n >> 1) & 3);                // physical slot
      uint4 qh, ql;
      qh.x = pk16(sh[kc + c * 8 + 0][n], sh[kc + c * 8 + 1][n]);
      qh.y = pk16(sh[kc + c * 8 + 2][n], sh[kc + c * 8 + 3][n]);
      qh.z = pk16(sh[kc + c * 8 + 4][n], sh[kc + c * 8 + 5][n]);
      qh.w = pk16(sh[kc + c * 8 + 6][n], sh[kc + c * 8 + 7][n]);
      ql.x = pk16(sl[kc + c * 8 + 0][n], sl[kc + c * 8 + 1][n]);
      ql.y = pk16(sl[kc + c * 8 + 2][n], sl[kc + c * 8 + 3][n]);
      ql.z = pk16(sl[kc + c * 8 + 4][n], sl[kc + c * 8 + 5][n]);
      ql.w = pk16(sl[kc + c * 8 + 6][n], sl[kc + c * 8 + 7][n]);
      *(uint4*)(tb + (size_t)n * 32 + sp * 8)        = qh;   // comp 0
      *(uint4*)(tb + 4096 + (size_t)n * 32 + sp * 8) = ql;   // comp 1
    }
  }
}

// ---------------- GEMM: r15 exact (best known: 85.7 total, absmax 0)
__global__ __launch_bounds__(256) void gemm_kernel(const float* __restrict__ x,
                                                   char* __restrict__ wsb) {
  const _Float16* wt = (const _Float16*)(wsb + OFF_WT);
  float* partial = (float*)(wsb + OFF_PART);
  const int bid = blockIdx.x;
  const int split = bid & 7;                 // consecutive bids -> XCD round-robin
  const int row0 = (bid >> 3) * BM;
  const int tile0 = tile0_of(split);
  const int ks = tile0 * 32;
  const int niter = niter_of(split);

  __shared__ float alds[3][64][32];          // 24 KB, swizzled
  __shared__ _Float16 wlds[2][128][32];      // 16 KB single buffer

  const int tid = threadIdx.x;
  const int lane = tid & 63;
  const int wid = tid >> 6;
  const int wm = wid & 1;                    // row half (32)
  const int wn = wid >> 1;                   // col half (64)

  const int rowlane = lane >> 5;
  const int up = (lane >> 2) & 7;
  const int fof = lane & 3;
  const float* xsrc[8];
#pragma unroll
  for (int j = 0; j < 8; ++j) {
    int row = wid * 16 + 2 * j + rowlane;
    int koff = ((up ^ (row & 7)) << 2) + fof;
    xsrc[j] = x + (size_t)(row0 + row) * KDIM + koff;
  }
  auto stageX = [&](int buf, int kb) {
    if (kb + BK <= KDIM) {
#pragma unroll
      for (int j = 0; j < 8; ++j)
        gload_lds4((const void*)(xsrc[j] + kb), (void*)&alds[buf][wid * 16 + 2 * j][0]);
    } else {
#pragma unroll
      for (int j = 0; j < 8; ++j) {
        int row = wid * 16 + 2 * j + rowlane;
        int k = kb + ((up ^ (row & 7)) << 2) + fof;
        float v = (k < KDIM) ? x[(size_t)(row0 + row) * KDIM + k] : 0.f;
        alds[buf][row][lane & 31] = v;
      }
    }
  };

  auto stageW = [&](int tile) {
    const _Float16* src = wt + (size_t)tile * 8192 + (size_t)wid * 2048 + (size_t)lane * 8;
#pragma unroll
    for (int c = 0; c < 4; ++c) {
      int chunk = wid * 4 + c;
      gload_lds16((const void*)(src + c * 512),
                  (void*)((char*)&wlds[0][0][0] + chunk * 1024));
    }
  };

  f32x4 accA[2][4], accB[2][4];
#pragma unroll
  for (int mt = 0; mt < 2; ++mt)
#pragma unroll
    for (int nt = 0; nt < 4; ++nt) { accA[mt][nt] = (f32x4)(0.f); accB[mt][nt] = (f32x4)(0.f); }

  const int fr = lane & 15;
  const int fslot = lane >> 4;

  stageW(tile0);
  stageX(0, ks);
  stageX(1, ks + BK);
  asm volatile("s_waitcnt vmcnt(8) lgkmcnt(0)" ::: "memory");
  __builtin_amdgcn_s_barrier();

  int xbuf = 0;
  for (int t = 0; t < niter; ++t) {
    float4 fa[2], fb[2];
    half8 b_h[4], b_l[4];
#pragma unroll
    for (int mt = 0; mt < 2; ++mt) {
      int row = wm * 32 + mt * 16 + fr;
      int u0 = (2 * fslot) ^ (row & 7);
      int u1 = (2 * fslot + 1) ^ (row & 7);
      fa[mt] = *(const float4*)&alds[xbuf][row][u0 * 4];
      fb[mt] = *(const float4*)&alds[xbuf][row][u1 * 4];
    }
#pragma unroll
    for (int nt = 0; nt < 4; ++nt) {
      int col = wn * 64 + nt * 16 + fr;
      int sp = fslot ^ ((col >> 1) & 3);
      b_h[nt] = *(const half8*)&wlds[0][col][sp * 8];
      b_l[nt] = *(const half8*)&wlds[1][col][sp * 8];
    }
    asm volatile("s_waitcnt lgkmcnt(0)" ::: "memory");
    __builtin_amdgcn_s_barrier();

    if (t + 1 < niter) stageW(tile0 + t + 1);
    if (t + 2 < niter) {
      int nb = xbuf + 2; if (nb >= 3) nb -= 3;
      stageX(nb, ks + (t + 2) * BK);
    }
    __builtin_amdgcn_sched_barrier(0);

    half8 a_h[2], a_l[2];
#pragma unroll
    for (int mt = 0; mt < 2; ++mt) {
      float fv[8] = {fa[mt].x, fa[mt].y, fa[mt].z, fa[mt].w,
                     fb[mt].x, fb[mt].y, fb[mt].z, fb[mt].w};
#pragma unroll
      for (int i = 0; i < 8; ++i) {
        _Float16 h = (_Float16)fv[i];
        a_h[mt][i] = h;
        a_l[mt][i] = (_Float16)((fv[i] - (float)h) * 2048.0f);
      }
    }
    __builtin_amdgcn_s_setprio(1);
#pragma unroll
    for (int mt = 0; mt < 2; ++mt)
#pragma unroll
      for (int nt = 0; nt < 4; ++nt) {
        accA[mt][nt] = __builtin_amdgcn_mfma_f32_16x16x32_f16(a_h[mt], b_h[nt], accA[mt][nt], 0, 0, 0);
        accB[mt][nt] = __builtin_amdgcn_mfma_f32_16x16x32_f16(a_l[mt], b_h[nt], accB[mt][nt], 0, 0, 0);
        accB[mt][nt] = __builtin_amdgcn_mfma_f32_16x16x32_f16(a_h[mt], b_l[nt], accB[mt][nt], 0, 0, 0);
      }
    __builtin_amdgcn_s_setprio(0);

    if (t + 1 < niter) {
      if (t + 2 < niter)
        asm volatile("s_waitcnt vmcnt(8) lgkmcnt(0)" ::: "memory");
      else
        asm volatile("s_waitcnt vmcnt(0) lgkmcnt(0)" ::: "memory");
      __builtin_amdgcn_s_barrier();
    }
    ++xbuf; if (xbuf >= 3) xbuf = 0;
  }

  float* pb = partial + (size_t)split * BSZ * NPAD;
#pragma unroll
  for (int mt = 0; mt < 2; ++mt)
#pragma unroll
    for (int nt = 0; nt < 4; ++nt) {
      int col = wn * 64 + nt * 16 + fr;
#pragma unroll
      for (int r = 0; r < 4; ++r) {
        int row = row0 + wm * 32 + mt * 16 + fslot * 4 + r;
        pb[(size_t)row * NPAD + col] = accA[mt][nt][r] + accB[mt][nt][r] * (1.0f / 2048.0f);
      }
    }
}

// ---------------- fused reduce + epilogue: 256 blocks x 16 samples (4x CU coverage)
__device__ __forceinline__ void axis_mask(const float a[WD], int lo, int hi, float m[WD]) {
  float am[WD];
  float tot = 0.f;
#pragma unroll
  for (int c = 0; c < WD; ++c) { am[c] = (c >= lo) ? a[c] : 0.f; tot += am[c]; }
  float run = 0.f;
  float c1[WD];
#pragma unroll
  for (int c = 0; c < WD; ++c) {
    run += am[c] / tot;
    c1[c] = (run >= 0.3f) ? run : 0.f;
  }
  float tot2 = 0.f;
#pragma unroll
  for (int c = 0; c < WD; ++c) { am[c] = (c < hi) ? a[c] : 0.f; tot2 += am[c]; }
  run = 0.f;
#pragma unroll
  for (int c = 0; c < WD; ++c) {
    run += am[c] / tot2;
    float c2 = 1.f - run;
    c2 = (c2 >= 0.3f) ? c2 : 0.f;
    m[c] = c1[c] * c2;
  }
}

__global__ __launch_bounds__(256) void epi_kernel(const char* __restrict__ wsb,
                                                  const float* __restrict__ keypoint,
                                                  float* __restrict__ out) {
  __shared__ float vlds[16][132];            // 16 samples, padded rows
  const int b0 = blockIdx.x * 16;
  const int tid = threadIdx.x;
  const float4* part4 = (const float4*)(wsb + OFF_PART);
  const float4* bias4 = (const float4*)(wsb + OFF_BIAS);

  // phase 1: reduce 16x128 floats = 512 float4; 2 per thread
  float4 a[2];
#pragma unroll
  for (int j = 0; j < 2; ++j) {
    int fi = tid * 2 + j;                    // row = fi>>5 (0..15), c4 = fi&31
    a[j] = part4[((size_t)(b0 + (fi >> 5))) * 32 + (fi & 31)];
  }
  for (int sp = 1; sp < SPLITK; ++sp) {
#pragma unroll
    for (int j = 0; j < 2; ++j) {
      int fi = tid * 2 + j;
      float4 p = part4[((size_t)sp * BSZ + b0 + (fi >> 5)) * 32 + (fi & 31)];
      a[j].x += p.x; a[j].y += p.y; a[j].z += p.z; a[j].w += p.w;
    }
  }
#pragma unroll
  for (int j = 0; j < 2; ++j) {
    int fi = tid * 2 + j;
    float4 bb = bias4[fi & 31];
    a[j].x += bb.x; a[j].y += bb.y; a[j].z += bb.z; a[j].w += bb.w;
    *(float4*)&vlds[fi >> 5][(fi & 31) * 4] = a[j];
  }
  __syncthreads();

  // phase 2: 80 units = 5 fams x 16 samples; fam-grouped (fam = tid>>4)
  if (tid < 80) {
    int fam = tid >> 4;
    int bl = tid & 15;
    int b = b0 + bl;
    const int G = (fam == 4) ? 1 : 2;
    const int nk = (fam == 4) ? 2 : 4;
    const float* vv = &vlds[bl][fam * 28];

    int mnx = 7, mxx = -1, mny = 7, mxy = -1;
    for (int i = 0; i < nk; ++i) {
      int kidx = KIDX[fam][i];
      float fx = keypoint[((size_t)b * 17 + kidx) * 2 + 0];
      float fy = keypoint[((size_t)b * 17 + kidx) * 2 + 1];
      int ix = (int)floorf(fx * 7.0f); ix = ix < 6 ? ix : 6;
      int iy = (int)floorf(fy * 7.0f); iy = iy < 6 ? iy : 6;
      mnx = min(mnx, ix); mxx = max(mxx, ix);
      mny = min(mny, iy); mxy = max(mxy, iy);
    }
    int lox = mnx - 1; if (lox < 0) lox = 0;
    int hix = mxx + 1; if (hix > 6) hix = 6;
    int loy = mny - 1; if (loy < 0) loy = 0;
    int hiy = mxy + 1; if (hiy > 6) hiy = 6;

    float xmg[2][WD], ymg[2][WD];
    float mx = 0.f;
#pragma unroll
    for (int g = 0; g < 2; ++g) {
      if (g < G) {
        const float* vg = vv + g * 14;
        float a0[WD], a1[WD];
#pragma unroll
        for (int c = 0; c < WD; ++c) {
          float s0 = vg[c], s1 = vg[c + 7];
          float mM = fmaxf(s0, s1);
          float e0 = expf(s0 - mM), e1 = expf(s1 - mM);
          float sum = e0 + e1;
          a0[c] = expf(e0 / sum);
          a1[c] = expf(e1 / sum);
        }
        axis_mask(a0, lox, hix, xmg[g]);
        axis_mask(a1, loy, hiy, ymg[g]);
        float mx_x = 0.f, mx_y = 0.f;
#pragma unroll
        for (int c = 0; c < WD; ++c) {
          mx_x = fmaxf(mx_x, xmg[g][c]);
          mx_y = fmaxf(mx_y, ymg[g][c]);
        }
        mx = fmaxf(mx, mx_y * mx_x);
      }
    }

    float d = mx + 1e-7f;
    float* op = out + OBASE[fam] + (size_t)b * (G * 49);
#pragma unroll
    for (int g = 0; g < 2; ++g) {
      if (g < G) {
#pragma unroll
        for (int y = 0; y < WD; ++y) {
          float yv = ymg[g][y];
#pragma unroll
          for (int xx = 0; xx < WD; ++xx) {
            op[g * 49 + y * 7 + xx] = (yv * xmg[g][xx]) / d;
          }
        }
      }
    }
  }
}

extern "C" void kernel_launch(void* const* d_in, const int* in_sizes, int n_in,
                              void* d_out, int out_size, void* d_ws, size_t ws_size,
                              hipStream_t stream) {
  const float* x        = (const float*)d_in[0];
  const float* keypoint = (const float*)d_in[1];
  const float* Wh = (const float*)d_in[2];
  const float* bh = (const float*)d_in[3];
  const float* Wa = (const float*)d_in[4];
  const float* ba = (const float*)d_in[5];
  const float* Wu = (const float*)d_in[6];
  const float* bu = (const float*)d_in[7];
  const float* Wl = (const float*)d_in[8];
  const float* bl = (const float*)d_in[9];
  const float* Wf = (const float*)d_in[10];
  const float* bf = (const float*)d_in[11];
  float* out = (float*)d_out;
  char* wsb  = (char*)d_ws;

  const int packBlocks = (NTILES * 32 + 63) / 64;   // 131
  hipLaunchKernelGGL(pack_kernel, dim3(packBlocks), dim3(256), 0, stream,
                     Wh, bh, Wa, ba, Wu, bu, Wl, bl, Wf, bf, wsb);
  hipLaunchKernelGGL(gemm_kernel, dim3((BSZ / BM) * SPLITK), dim3(256), 0, stream, x, wsb);
  hipLaunchKernelGGL(epi_kernel, dim3(BSZ / 16), dim3(256), 0, stream,
                     wsb, keypoint, out);
}